// Round 9
// baseline (174.115 us; speedup 1.0000x reference)
//
#include <hip/hip_runtime.h>

#define NIMG    4991
#define RIRLEN  3968
#define NT      512          // 8 waves per block
#define NBL     38           // local ti0 buckets, width 16
#define INV_PI  0.31830988618379067f
#define SR_OVER_C 46.647230320699704f   // 16000 / 343

// ---- compile-time compact image-source table: all (x,y,z), |x|+|y|+|z| <= 15 ----
struct Tab { int v[NIMG]; };
static constexpr Tab make_tab() {
    Tab t{};
    int k = 0;
    for (int x = -15; x <= 15; ++x)
        for (int y = -15; y <= 15; ++y)
            for (int z = -15; z <= 15; ++z) {
                int ax = x < 0 ? -x : x;
                int ay = y < 0 ? -y : y;
                int az = z < 0 ? -z : z;
                if (ax + ay + az <= 15)
                    t.v[k++] = (x + 15) | ((y + 15) << 8) | ((z + 15) << 16);
            }
    return t;
}
__constant__ Tab c_tab = make_tab();

static __device__ __forceinline__ int iabs(int v) { return v < 0 ? -v : v; }

// ============================================================================
// Fully fused kernel. Block = (batch b, window-group g of 8 contiguous
// 64-bin output windows). The block:
//  1. recomputes batch params (redundant across the 8 groups -- cheap),
//  2. pass A: histograms ti0 of images relevant to ITS windows
//     (local coord lc = ti0-(512g-96) in [16, 608)) into 38 width-16 buckets,
//  3. serial prefix-sum (38 entries), pass B: computes {delay, Hp} per image
//     and scatters bucket-sorted into LDS (8 B/entry, worst case 4991 fits),
//  4. wave w owns window wi = 8g+w: EVALs exactly its bucket range
//     [off[4w+1], off[4w+10]) from LDS (uniform broadcast ds_read_b64),
//     accumulating 64 bins in a register, then ONE plain coalesced store.
// Windows partition the output -> no atomics, no zeroing, no workspace.
// Math (verified R5-R7): with c1p = amp*(-1)^di*sin(pi*frac)/pi, Hp = 0.5*c1p,
// v(t) = (-1)^t * Hp*(1 + cos_t*cd + sin_t*sd) / (t-delay),
// cd/sd = cos/sin(2*pi*fract(delay/80)) reconstructed per-EVAL.
//
// frac==0 (exact-integer delay; happens ~dozens of times per dataset):
// R8 BUG: fixed nudge 2^-14 < ulp(di)/2 for di>=1024 -> di-frac rounded back
// to di -> xw==0 -> rcp(0)=inf. FIX: RELATIVE nudge frac = di*2^-16
// (always 128-256 ulps of di -> di-frac strictly below di); tap error
// <= amp*(pi*di*2^-16)^2/6 ~ 7e-5 absolute. Plus an xw==0 zero-guard in
// EVAL as insurance (drops a tap instead of producing inf).
// ============================================================================
__global__ __launch_bounds__(NT)
void rir_fused(const float* __restrict__ inp, float* __restrict__ out, int B) {
    const int bx   = blockIdx.x;
    const int b    = bx >> 3;
    const int g    = bx & 7;
    const int tid  = threadIdx.x;
    const int lane = tid & 63;
    const int wv   = tid >> 6;               // 0..7
    const int tbase = (g << 9) - 96;         // local-coord origin for ti0

    __shared__ float2 s_img[NIMG];           // bucket-sorted {delay, Hp}
    __shared__ float  s_par[12];
    __shared__ int    s_hist[NBL];
    __shared__ int    s_off[NBL + 1];
    __shared__ int    s_cur[NBL];

    if (tid < NBL) s_hist[tid] = 0;
    if (tid == 0) {
        const float* ip = inp + b * 12;
        float rx = ip[0], ry = ip[1], rz = ip[2];
        float mx = ip[3] * rx, my = ip[4] * ry, mz = ip[5] * rz;
        float sx = ip[6] * rx, sy = ip[7] * ry, sz = ip[8] * rz;
        float aw = __builtin_fmaf(ip[9],  0.84f, 0.01f);
        float a4 = __builtin_fmaf(ip[10], 0.84f, 0.01f);
        float a5 = __builtin_fmaf(ip[11], 0.84f, 0.01f);
        s_par[0] = rx; s_par[1] = ry; s_par[2] = rz;
        s_par[3] = mx; s_par[4] = my; s_par[5] = mz;
        s_par[6] = sx; s_par[7] = sy; s_par[8] = sz;
        s_par[9]  = 0.5f * __builtin_amdgcn_logf(1.0f - aw);   // log2(tr)
        s_par[10] = 0.5f * __builtin_amdgcn_logf(1.0f - a4);
        s_par[11] = 0.5f * __builtin_amdgcn_logf(1.0f - a5);
        if (g == 0) {   // toa output, once per batch
            float dx = mx - sx, dy = my - sy, dz = mz - sz;
            out[(size_t)B * RIRLEN + b] = __builtin_fmaf(
                __builtin_sqrtf(dx * dx + dy * dy + dz * dz), SR_OVER_C, 40.0f);
        }
    }
    __syncthreads();

    const float rx = s_par[0], ry = s_par[1], rz = s_par[2];
    const float mx = s_par[3], my = s_par[4], mz = s_par[5];
    const float sx = s_par[6], sy = s_par[7], sz = s_par[8];
    const float lw = s_par[9], l4 = s_par[10], l5 = s_par[11];

    // ---- pass A: histogram of relevant images (cheap geometry only) ----
    for (int idx = tid; idx < NIMG; idx += NT) {
        const int p = c_tab.v[idx];
        const int x = (p & 255) - 15;
        const int y = ((p >> 8) & 255) - 15;
        const int z = ((p >> 16) & 255) - 15;
        const float ix = (x & 1) ? __builtin_fmaf(rx, (float)(x + 1), -sx)
                                 : __builtin_fmaf(rx, (float)x, sx);
        const float iy = (y & 1) ? __builtin_fmaf(ry, (float)(y + 1), -sy)
                                 : __builtin_fmaf(ry, (float)y, sy);
        const float iz = (z & 1) ? __builtin_fmaf(rz, (float)(z + 1), -sz)
                                 : __builtin_fmaf(rz, (float)z, sz);
        const float dx = ix - mx, dy = iy - my, dz = iz - mz;
        const float dist  = __builtin_sqrtf(__builtin_fmaf(dx, dx, __builtin_fmaf(dy, dy, dz * dz)));
        const float delay = dist * SR_OVER_C;
        const int   ti0   = (int)__builtin_ceilf(delay) - 40;
        const int   lc    = ti0 - tbase;
        if (ti0 < RIRLEN && (unsigned)(lc - 16) < 592u)
            atomicAdd(&s_hist[lc >> 4], 1);
    }
    __syncthreads();

    // ---- serial exclusive scan over 38 buckets (trivial) ----
    if (tid == 0) {
        int a = 0;
        #pragma unroll
        for (int k = 0; k < NBL; ++k) { s_off[k] = a; a += s_hist[k]; }
        s_off[NBL] = a;
    }
    __syncthreads();
    if (tid < NBL) s_cur[tid] = s_off[tid];
    __syncthreads();

    // ---- pass B: full params, scatter bucket-sorted into LDS ----
    for (int idx = tid; idx < NIMG; idx += NT) {
        const int p = c_tab.v[idx];
        const int x = (p & 255) - 15;
        const int y = ((p >> 8) & 255) - 15;
        const int z = ((p >> 16) & 255) - 15;
        const float ix = (x & 1) ? __builtin_fmaf(rx, (float)(x + 1), -sx)
                                 : __builtin_fmaf(rx, (float)x, sx);
        const float iy = (y & 1) ? __builtin_fmaf(ry, (float)(y + 1), -sy)
                                 : __builtin_fmaf(ry, (float)y, sy);
        const float iz = (z & 1) ? __builtin_fmaf(rz, (float)(z + 1), -sz)
                                 : __builtin_fmaf(rz, (float)z, sz);
        const float dx = ix - mx, dy = iy - my, dz = iz - mz;
        const float dist  = __builtin_sqrtf(__builtin_fmaf(dx, dx, __builtin_fmaf(dy, dy, dz * dz)));
        const float delay = dist * SR_OVER_C;
        const float di    = __builtin_ceilf(delay);
        const int   ti0   = (int)di - 40;
        const int   lc    = ti0 - tbase;
        if (!(ti0 < RIRLEN && (unsigned)(lc - 16) < 592u)) continue;

        const int ew = iabs(x >> 1) + iabs((x + 1) >> 1) + iabs(y >> 1) + iabs((y + 1) >> 1);
        const float att = __builtin_amdgcn_exp2f(__builtin_fmaf((float)ew, lw,
                              __builtin_fmaf((float)iabs(z >> 1), l4,
                                   (float)iabs((z + 1) >> 1) * l5)));
        const float amp = att * __builtin_amdgcn_rcpf(dist);
        float frac = di - delay;                       // in [0,1), exact (Sterbenz)
        // RELATIVE nudge: di*2^-16 is 128-256 ulps of di at any magnitude,
        // so fl(di - frac) < di strictly -> xw != 0 at t = di.
        if (frac == 0.0f) frac = di * 1.52587890625e-05f;
        const int dii = (int)di;
        float c1p = amp * __builtin_amdgcn_sinf(0.5f * frac) * INV_PI;  // sin(pi*frac)/pi
        if (dii & 1) c1p = -c1p;

        const int slot = atomicAdd(&s_cur[lc >> 4], 1);
        s_img[slot] = make_float2(di - frac, 0.5f * c1p);   // {delay, Hp}
    }
    __syncthreads();

    // ---- phase 3: wave wv owns window wi; register-gather from LDS ----
    const int wi = (g << 3) + wv;
    if (wi >= 62) return;                       // after the last barrier: safe
    const int lo = s_off[4 * wv + 1];
    const int hi = s_off[4 * wv + 10];

    const int   t    = (wi << 6) + lane;
    const float tf   = (float)t;
    const int   m    = t - (t / 80) * 80;       // t mod 80 (const-div)
    const float cth0 = __builtin_amdgcn_cosf((float)m * 0.0125f);
    const float sth0 = __builtin_amdgcn_sinf((float)m * 0.0125f);
    const float sl   = (lane & 1) ? -1.0f : 1.0f;   // (-1)^t, wi*64 even

    float acc = 0.0f;
    #pragma unroll 4
    for (int i = lo; i < hi; ++i) {
        const float2 e  = s_img[i];             // uniform ds_read_b64 broadcast
        const float  xw = tf - e.x;
        const float  rv = e.x * 0.0125f;        // delay/80
        const float  fr = rv - __builtin_floorf(rv);
        const float  cd = __builtin_amdgcn_cosf(fr);
        const float  sd = __builtin_amdgcn_sinf(fr);
        const float  u  = __builtin_fmaf(cth0, cd, __builtin_fmaf(sth0, sd, 1.0f));
        const float  hm = (__builtin_fabsf(xw) <= 40.0f) ? (e.y * u) : 0.0f;
        float v = hm * __builtin_amdgcn_rcpf(xw);
        v = (xw == 0.0f) ? 0.0f : v;            // insurance: drop tap, never inf
        acc += v;
    }
    out[(size_t)b * RIRLEN + t] = sl * acc;     // plain coalesced store
}

extern "C" void kernel_launch(void* const* d_in, const int* in_sizes, int n_in,
                              void* d_out, int out_size, void* d_ws, size_t ws_size,
                              hipStream_t stream) {
    (void)d_ws; (void)ws_size; (void)n_in; (void)out_size;
    const float* inp = (const float*)d_in[0];
    float* out = (float*)d_out;
    const int B = in_sizes[0] / 12;
    // single kernel: no memset, no workspace, no second launch
    rir_fused<<<dim3(B * 8), dim3(NT), 0, stream>>>(inp, out, B);
}

// Round 11
// 111.338 us; speedup vs baseline: 1.5639x; 1.5639x over previous
//
#include <hip/hip_runtime.h>

#define NIMG    4991
#define RIRLEN  3968
#define NT      512          // 8 waves per block
#define NGRP    4            // window groups per batch (grid = B*4)
#define INV_PI  0.31830988618379067f
#define SR_OVER_C 46.647230320699704f   // 16000 / 343

// ---- compile-time compact image-source table: all (x,y,z), |x|+|y|+|z| <= 15 ----
struct Tab { int v[NIMG]; };
static constexpr Tab make_tab() {
    Tab t{};
    int k = 0;
    for (int x = -15; x <= 15; ++x)
        for (int y = -15; y <= 15; ++y)
            for (int z = -15; z <= 15; ++z) {
                int ax = x < 0 ? -x : x;
                int ay = y < 0 ? -y : y;
                int az = z < 0 ? -z : z;
                if (ax + ay + az <= 15)
                    t.v[k++] = (x + 15) | ((y + 15) << 8) | ((z + 15) << 16);
            }
    return t;
}
__constant__ Tab c_tab = make_tab();

static __device__ __forceinline__ int iabs(int v) { return v < 0 ? -v : v; }

// NOTE (R10 fix): __builtin_amdgcn_cvt_pkrtz returns
// '__fp16 __attribute__((ext_vector_type(2)))' -- must typedef with __fp16,
// not _Float16 (distinct vector types to clang; no implicit conversion).
typedef __fp16 f16x2 __attribute__((ext_vector_type(2)));

// ============================================================================
// Fused kernel v11 (recompile of the R10 design). Block = (batch b, group g).
// All 4 blocks of a batch bucket-sort the FULL live image list into LDS
// (global width-16 ti0 buckets); wave wv evals windows wi = g+4*wv and wi+32
// (interleaved -> per-block work uniform; grid B*4 = 512 = 2 blocks/CU).
//
// Entry: s_dh[i] = {delay, Hp}, s_cs[i] = packed f16 {cd, sd}:
//   c1p = amp * (-1)^di * sin(pi*frac)/pi,  Hp = 0.5*c1p
//   cd,sd = cos,sin(2*pi*fract(delay/80))   (computed ONCE per image, f16)
// EVAL: u = 1 + cth0*cd + sth0*sd (hann via angle addition)
//   v = (-1)^t * Hp * u / (t - delay),  masked to |t-delay| <= 40.
// -> 1 trans (rcp) per EVAL instead of R9's 3 (cos+sin+rcp): R9 counters
//    showed trans-issue ~ 59us = VALUBusy 45% of 130us; this cuts it ~2.5x.
//
// Sort atomics: 4-way sub-histograms/cursors indexed by lane&3 (adjacent
// lanes hit the same bucket; 4 addresses cut DS serialization 4x). Pass A/B
// use the same idx->lane map so count and slot go through the same cursor.
//
// frac==0: relative nudge frac = di*2^-16 (R9-verified) + xw==0 zero-guard.
// ============================================================================
__global__ __launch_bounds__(NT)
void rir_fused(const float* __restrict__ inp, float* __restrict__ out, int B) {
    const int bx   = blockIdx.x;
    const int b    = bx >> 2;
    const int g    = bx & 3;
    const int tid  = threadIdx.x;
    const int lane = tid & 63;
    const int wv   = tid >> 6;               // 0..7
    const int q    = lane & 3;               // sub-histogram id

    __shared__ float2   s_dh[NIMG];          // bucket-sorted {delay, Hp}  (40KB)
    __shared__ unsigned s_cs[NIMG];          // packed f16 {cd, sd}        (20KB)
    __shared__ float    s_par[12];
    __shared__ int      s_h4[4][256];        // sub-histograms -> cursors  (4KB)
    __shared__ int      s_off[257];          // bucket offsets             (1KB)

    for (int k = tid; k < 1024; k += NT) ((int*)s_h4)[k] = 0;
    if (tid == 0) {
        const float* ip = inp + b * 12;
        float rx = ip[0], ry = ip[1], rz = ip[2];
        float mx = ip[3] * rx, my = ip[4] * ry, mz = ip[5] * rz;
        float sx = ip[6] * rx, sy = ip[7] * ry, sz = ip[8] * rz;
        float aw = __builtin_fmaf(ip[9],  0.84f, 0.01f);
        float a4 = __builtin_fmaf(ip[10], 0.84f, 0.01f);
        float a5 = __builtin_fmaf(ip[11], 0.84f, 0.01f);
        s_par[0] = rx; s_par[1] = ry; s_par[2] = rz;
        s_par[3] = mx; s_par[4] = my; s_par[5] = mz;
        s_par[6] = sx; s_par[7] = sy; s_par[8] = sz;
        s_par[9]  = 0.5f * __builtin_amdgcn_logf(1.0f - aw);   // log2(tr)
        s_par[10] = 0.5f * __builtin_amdgcn_logf(1.0f - a4);
        s_par[11] = 0.5f * __builtin_amdgcn_logf(1.0f - a5);
        if (g == 0) {   // toa output, once per batch
            float dx = mx - sx, dy = my - sy, dz = mz - sz;
            out[(size_t)B * RIRLEN + b] = __builtin_fmaf(
                __builtin_sqrtf(dx * dx + dy * dy + dz * dz), SR_OVER_C, 40.0f);
        }
    }
    __syncthreads();

    const float rx = s_par[0], ry = s_par[1], rz = s_par[2];
    const float mx = s_par[3], my = s_par[4], mz = s_par[5];
    const float sx = s_par[6], sy = s_par[7], sz = s_par[8];
    const float lw = s_par[9], l4 = s_par[10], l5 = s_par[11];

    // ---- pass A: histogram (geometry only); bucket = (ti0+96)>>4 in [3,253] ----
    for (int idx = tid; idx < NIMG; idx += NT) {
        const int p = c_tab.v[idx];
        const int x = (p & 255) - 15;
        const int y = ((p >> 8) & 255) - 15;
        const int z = ((p >> 16) & 255) - 15;
        const float ix = (x & 1) ? __builtin_fmaf(rx, (float)(x + 1), -sx)
                                 : __builtin_fmaf(rx, (float)x, sx);
        const float iy = (y & 1) ? __builtin_fmaf(ry, (float)(y + 1), -sy)
                                 : __builtin_fmaf(ry, (float)y, sy);
        const float iz = (z & 1) ? __builtin_fmaf(rz, (float)(z + 1), -sz)
                                 : __builtin_fmaf(rz, (float)z, sz);
        const float dx = ix - mx, dy = iy - my, dz = iz - mz;
        const float dist  = __builtin_sqrtf(__builtin_fmaf(dx, dx, __builtin_fmaf(dy, dy, dz * dz)));
        const float delay = dist * SR_OVER_C;
        const int   ti0   = (int)__builtin_ceilf(delay) - 40;
        if (ti0 < RIRLEN) atomicAdd(&s_h4[q][(ti0 + 96) >> 4], 1);
    }
    __syncthreads();

    // ---- reduce sub-histograms + exclusive scan (Hillis-Steele over 256) ----
    if (tid < 256)
        s_off[tid + 1] = s_h4[0][tid] + s_h4[1][tid] + s_h4[2][tid] + s_h4[3][tid];
    if (tid == 0) s_off[0] = 0;
    __syncthreads();
    for (int d = 1; d < 256; d <<= 1) {
        int tv = 0;
        if (tid < 256 && tid >= d) tv = s_off[tid + 1 - d];
        __syncthreads();
        if (tid < 256 && tid >= d) s_off[tid + 1] += tv;
        __syncthreads();
    }
    // turn sub-histograms into sub-cursors in place
    if (tid < 256) {
        int run = s_off[tid];
        #pragma unroll
        for (int p = 0; p < 4; ++p) {
            const int c = s_h4[p][tid];
            s_h4[p][tid] = run;
            run += c;
        }
    }
    __syncthreads();

    // ---- pass B: full params, scatter bucket-sorted into LDS ----
    for (int idx = tid; idx < NIMG; idx += NT) {
        const int p = c_tab.v[idx];
        const int x = (p & 255) - 15;
        const int y = ((p >> 8) & 255) - 15;
        const int z = ((p >> 16) & 255) - 15;
        const float ix = (x & 1) ? __builtin_fmaf(rx, (float)(x + 1), -sx)
                                 : __builtin_fmaf(rx, (float)x, sx);
        const float iy = (y & 1) ? __builtin_fmaf(ry, (float)(y + 1), -sy)
                                 : __builtin_fmaf(ry, (float)y, sy);
        const float iz = (z & 1) ? __builtin_fmaf(rz, (float)(z + 1), -sz)
                                 : __builtin_fmaf(rz, (float)z, sz);
        const float dx = ix - mx, dy = iy - my, dz = iz - mz;
        const float dist  = __builtin_sqrtf(__builtin_fmaf(dx, dx, __builtin_fmaf(dy, dy, dz * dz)));
        const float delay = dist * SR_OVER_C;
        const float di    = __builtin_ceilf(delay);
        const int   ti0   = (int)di - 40;
        if (ti0 >= RIRLEN) continue;

        const int ew = iabs(x >> 1) + iabs((x + 1) >> 1) + iabs(y >> 1) + iabs((y + 1) >> 1);
        const float att = __builtin_amdgcn_exp2f(__builtin_fmaf((float)ew, lw,
                              __builtin_fmaf((float)iabs(z >> 1), l4,
                                   (float)iabs((z + 1) >> 1) * l5)));
        const float amp = att * __builtin_amdgcn_rcpf(dist);
        float frac = di - delay;                       // in [0,1), exact (Sterbenz)
        if (frac == 0.0f) frac = di * 1.52587890625e-05f;   // relative nudge (R9)
        const int dii = (int)di;
        float c1p = amp * __builtin_amdgcn_sinf(0.5f * frac) * INV_PI;  // sin(pi*frac)/pi
        if (dii & 1) c1p = -c1p;
        const float dstore = di - frac;

        const float rv = dstore * 0.0125f;             // delay/80
        const float fr = rv - __builtin_floorf(rv);
        const float cd = __builtin_amdgcn_cosf(fr);    // revolutions
        const float sd = __builtin_amdgcn_sinf(fr);
        const f16x2 pk2 = __builtin_amdgcn_cvt_pkrtz(cd, sd);

        const int slot = atomicAdd(&s_h4[q][(ti0 + 96) >> 4], 1);
        s_dh[slot] = make_float2(dstore, 0.5f * c1p);
        s_cs[slot] = __builtin_bit_cast(unsigned, pk2);
    }
    __syncthreads();

    // ---- EVAL: wave wv owns windows g+4wv and g+4wv+32 (interleaved) ----
    #pragma unroll
    for (int ws = 0; ws < 2; ++ws) {
        const int wi = g + 4 * wv + 32 * ws;
        if (wi >= 62) break;                 // no barriers after: safe
        const int lo = s_off[4 * wi + 1];
        const int hi = s_off[4 * wi + 10];

        const int   t    = (wi << 6) + lane;
        const float tf   = (float)t;
        const int   m    = t - (t / 80) * 80;           // t mod 80
        const float cth0 = __builtin_amdgcn_cosf((float)m * 0.0125f);
        const float sth0 = __builtin_amdgcn_sinf((float)m * 0.0125f);
        const float sl   = (lane & 1) ? -1.0f : 1.0f;   // (-1)^t, wi*64 even

        float acc = 0.0f;
        #pragma unroll 4
        for (int i = lo; i < hi; ++i) {
            const float2   e  = s_dh[i];     // uniform ds_read_b64 broadcast
            const unsigned pk = s_cs[i];     // uniform ds_read_b32 broadcast
            const f16x2    h  = __builtin_bit_cast(f16x2, pk);
            const float xw = tf - e.x;
            const float u  = __builtin_fmaf(cth0, (float)h.x,
                                 __builtin_fmaf(sth0, (float)h.y, 1.0f));
            const float hm = (__builtin_fabsf(xw) <= 40.0f) ? (e.y * u) : 0.0f;
            float v = hm * __builtin_amdgcn_rcpf(xw);
            v = (xw == 0.0f) ? 0.0f : v;     // insurance: drop tap, never inf
            acc += v;
        }
        out[(size_t)b * RIRLEN + t] = sl * acc;         // plain coalesced store
    }
}

extern "C" void kernel_launch(void* const* d_in, const int* in_sizes, int n_in,
                              void* d_out, int out_size, void* d_ws, size_t ws_size,
                              hipStream_t stream) {
    (void)d_ws; (void)ws_size; (void)n_in; (void)out_size;
    const float* inp = (const float*)d_in[0];
    float* out = (float*)d_out;
    const int B = in_sizes[0] / 12;
    rir_fused<<<dim3(B * NGRP), dim3(NT), 0, stream>>>(inp, out, B);
}

// Round 12
// 105.225 us; speedup vs baseline: 1.6547x; 1.0581x over previous
//
#include <hip/hip_runtime.h>

#define NIMG    4991
#define RIRLEN  3968
#define NT      512          // 8 waves per block
#define NW      31           // windows per block (62 windows, 2 blocks/batch)
#define KPT     10           // images per thread (10*512 = 5120 >= 4991)
#define INV_PI  0.31830988618379067f
#define SR_OVER_C 46.647230320699704f   // 16000 / 343

// ---- compile-time compact image-source table: all (x,y,z), |x|+|y|+|z| <= 15 ----
struct Tab { int v[NIMG]; };
static constexpr Tab make_tab() {
    Tab t{};
    int k = 0;
    for (int x = -15; x <= 15; ++x)
        for (int y = -15; y <= 15; ++y)
            for (int z = -15; z <= 15; ++z) {
                int ax = x < 0 ? -x : x;
                int ay = y < 0 ? -y : y;
                int az = z < 0 ? -z : z;
                if (ax + ay + az <= 15)
                    t.v[k++] = (x + 15) | ((y + 15) << 8) | ((z + 15) << 16);
            }
    return t;
}
__constant__ Tab c_tab = make_tab();

static __device__ __forceinline__ int iabs(int v) { return v < 0 ? -v : v; }

// __builtin_amdgcn_cvt_pkrtz returns __fp16-based ext vector (R10 lesson).
typedef __fp16 f16x2 __attribute__((ext_vector_type(2)));

// ============================================================================
// Fused kernel v13. Block = (batch b, parity g). Grid = B*2 = 256 = 1/CU.
// Single geometry pass -> register arrays {delay,Hp} + packed f16 {Hp*cd,Hp*sd}
// (10 images/thread, fully unrolled = static reg indexing); LDS histogram of
// width-16 ti0 buckets (layout [bucket][q], q=lane&3 -> 4 consecutive banks);
// scan; scatter from registers into bucket-sorted LDS. Wave assignment of the
// block's 31 windows (wi = g+2k) by EXACT prefix-midpoint share of the known
// bucket lengths -> per-wave work balanced to +-half of the largest window.
// EVAL per image: xw = t-delay; pre = Hp + cth0*Hcd + sth0*Hsd (angle-add
// hann, f16 products -> v_fma_mix, no *Hp mul); v = masked(pre)*rcp(xw).
// xw==0 is impossible: natural frac -> Sterbenz makes dstore==delay exactly
// (< di strictly); frac==0 -> relative nudge di*2^-16 >= 64 ulps (R9-proven).
// Windows partition the output -> one plain coalesced store per window.
// ============================================================================
__global__ __launch_bounds__(NT)
void rir_fused(const float* __restrict__ inp, float* __restrict__ out, int B) {
    const int bx   = blockIdx.x;
    const int b    = bx >> 1;
    const int g    = bx & 1;
    const int tid  = threadIdx.x;
    const int lane = tid & 63;
    const int wv   = tid >> 6;               // 0..7
    const int q    = lane & 3;               // sub-cursor id

    __shared__ float2   s_dh[NIMG];          // bucket-sorted {delay, Hp}   (40KB)
    __shared__ unsigned s_cs[NIMG];          // packed f16 {Hp*cd, Hp*sd}   (20KB)
    __shared__ float    s_par[12];
    __shared__ int      s_h4[256][4];        // sub-hists -> cursors        (4KB)
    __shared__ int      s_off[257];          // bucket offsets              (1KB)

    for (int k = tid; k < 1024; k += NT) ((int*)s_h4)[k] = 0;
    if (tid == 0) {
        const float* ip = inp + b * 12;
        float rx = ip[0], ry = ip[1], rz = ip[2];
        float mx = ip[3] * rx, my = ip[4] * ry, mz = ip[5] * rz;
        float sx = ip[6] * rx, sy = ip[7] * ry, sz = ip[8] * rz;
        float aw = __builtin_fmaf(ip[9],  0.84f, 0.01f);
        float a4 = __builtin_fmaf(ip[10], 0.84f, 0.01f);
        float a5 = __builtin_fmaf(ip[11], 0.84f, 0.01f);
        s_par[0] = rx; s_par[1] = ry; s_par[2] = rz;
        s_par[3] = mx; s_par[4] = my; s_par[5] = mz;
        s_par[6] = sx; s_par[7] = sy; s_par[8] = sz;
        s_par[9]  = 0.5f * __builtin_amdgcn_logf(1.0f - aw);   // log2(tr)
        s_par[10] = 0.5f * __builtin_amdgcn_logf(1.0f - a4);
        s_par[11] = 0.5f * __builtin_amdgcn_logf(1.0f - a5);
        if (g == 0) {   // toa output, once per batch
            float dx = mx - sx, dy = my - sy, dz = mz - sz;
            out[(size_t)B * RIRLEN + b] = __builtin_fmaf(
                __builtin_sqrtf(dx * dx + dy * dy + dz * dz), SR_OVER_C, 40.0f);
        }
    }
    __syncthreads();

    const float rx = s_par[0], ry = s_par[1], rz = s_par[2];
    const float mx = s_par[3], my = s_par[4], mz = s_par[5];
    const float sx = s_par[6], sy = s_par[7], sz = s_par[8];
    const float lw = s_par[9], l4 = s_par[10], l5 = s_par[11];

    // ---- SINGLE geometry pass -> registers; histogram from registers ----
    float2   edh[KPT];
    unsigned ecs[KPT];
    int      bkt[KPT];
    #pragma unroll
    for (int k = 0; k < KPT; ++k) {
        bkt[k] = -1;
        const int idx = tid + k * NT;
        if (idx < NIMG) {
            const int p = c_tab.v[idx];
            const int x = (p & 255) - 15;
            const int y = ((p >> 8) & 255) - 15;
            const int z = ((p >> 16) & 255) - 15;
            const float ix = (x & 1) ? __builtin_fmaf(rx, (float)(x + 1), -sx)
                                     : __builtin_fmaf(rx, (float)x, sx);
            const float iy = (y & 1) ? __builtin_fmaf(ry, (float)(y + 1), -sy)
                                     : __builtin_fmaf(ry, (float)y, sy);
            const float iz = (z & 1) ? __builtin_fmaf(rz, (float)(z + 1), -sz)
                                     : __builtin_fmaf(rz, (float)z, sz);
            const float dx = ix - mx, dy = iy - my, dz = iz - mz;
            const float dist  = __builtin_sqrtf(
                __builtin_fmaf(dx, dx, __builtin_fmaf(dy, dy, dz * dz)));
            const float delay = dist * SR_OVER_C;
            const float di    = __builtin_ceilf(delay);
            const int   ti0   = (int)di - 40;
            if (ti0 < RIRLEN) {
                const int ew = iabs(x >> 1) + iabs((x + 1) >> 1)
                             + iabs(y >> 1) + iabs((y + 1) >> 1);
                const float att = __builtin_amdgcn_exp2f(__builtin_fmaf((float)ew, lw,
                                      __builtin_fmaf((float)iabs(z >> 1), l4,
                                           (float)iabs((z + 1) >> 1) * l5)));
                const float amp = att * __builtin_amdgcn_rcpf(dist);
                float frac = di - delay;                       // exact (Sterbenz)
                if (frac == 0.0f) frac = di * 1.52587890625e-05f;  // rel nudge
                const int dii = (int)di;
                float c1p = amp * __builtin_amdgcn_sinf(0.5f * frac) * INV_PI;
                if (dii & 1) c1p = -c1p;
                const float Hp     = 0.5f * c1p;
                const float dstore = di - frac;
                const float rv = dstore * 0.0125f;             // delay/80
                const float fr = rv - __builtin_floorf(rv);
                const float Hcd = Hp * __builtin_amdgcn_cosf(fr);  // revolutions
                const float Hsd = Hp * __builtin_amdgcn_sinf(fr);
                const f16x2 pk2 = __builtin_amdgcn_cvt_pkrtz(Hcd, Hsd);

                const int bk = (ti0 + 96) >> 4;                // in [3,253]
                bkt[k] = bk;
                edh[k] = make_float2(dstore, Hp);
                ecs[k] = __builtin_bit_cast(unsigned, pk2);
                atomicAdd(&s_h4[bk][q], 1);
            }
        }
    }
    __syncthreads();

    // ---- reduce sub-histograms + exclusive scan (Hillis-Steele over 256) ----
    if (tid < 256)
        s_off[tid + 1] = s_h4[tid][0] + s_h4[tid][1] + s_h4[tid][2] + s_h4[tid][3];
    if (tid == 0) s_off[0] = 0;
    __syncthreads();
    for (int d = 1; d < 256; d <<= 1) {
        int tv = 0;
        if (tid < 256 && tid >= d) tv = s_off[tid + 1 - d];
        __syncthreads();
        if (tid < 256 && tid >= d) s_off[tid + 1] += tv;
        __syncthreads();
    }
    if (tid < 256) {        // sub-histograms -> sub-cursors in place
        int run = s_off[tid];
        #pragma unroll
        for (int p = 0; p < 4; ++p) {
            const int c = s_h4[tid][p];
            s_h4[tid][p] = run;
            run += c;
        }
    }
    __syncthreads();

    // ---- scatter from registers into bucket-sorted LDS ----
    #pragma unroll
    for (int k = 0; k < KPT; ++k) {
        if (bkt[k] >= 0) {
            const int slot = atomicAdd(&s_h4[bkt[k]][q], 1);
            s_dh[slot] = edh[k];
            s_cs[slot] = ecs[k];
        }
    }
    __syncthreads();

    // ---- exact balance: total work of this block's 31 windows ----
    int T = 0;
    #pragma unroll
    for (int kk = 0; kk < NW; ++kk) {
        const int wi = g + 2 * kk;
        T += s_off[4 * wi + 10] - s_off[4 * wi + 1];
    }

    // ---- walk windows; wave owns those whose prefix-midpoint maps to it ----
    int P = 0;
    for (int kk = 0; kk < NW; ++kk) {
        const int wi  = g + 2 * kk;
        const int lo  = s_off[4 * wi + 1];
        const int hi  = s_off[4 * wi + 10];
        const int len = hi - lo;
        int owner = (T > 0)
            ? (int)((8u * (unsigned)(P + (len >> 1))) / (unsigned)T)
            : (kk >> 2);
        if (owner > 7) owner = 7;
        P += len;
        if (owner != wv) continue;

        const int   t    = (wi << 6) + lane;
        const float tf   = (float)t;
        const int   m    = t - (t / 80) * 80;           // t mod 80
        const float cth0 = __builtin_amdgcn_cosf((float)m * 0.0125f);
        const float sth0 = __builtin_amdgcn_sinf((float)m * 0.0125f);
        const float sl   = (lane & 1) ? -1.0f : 1.0f;   // (-1)^t, wi*64 even

        float acc = 0.0f;
        #pragma unroll 4
        for (int i = lo; i < hi; ++i) {
            const float2 e  = s_dh[i];                  // uniform b64 broadcast
            const f16x2  h  = __builtin_bit_cast(f16x2, s_cs[i]);  // b32
            const float xw  = tf - e.x;
            const float pre = __builtin_fmaf(cth0, (float)h.x,
                                  __builtin_fmaf(sth0, (float)h.y, e.y));
            const float hm  = (__builtin_fabsf(xw) <= 40.0f) ? pre : 0.0f;
            acc = __builtin_fmaf(hm, __builtin_amdgcn_rcpf(xw), acc);
        }
        out[(size_t)b * RIRLEN + t] = sl * acc;         // plain coalesced store
    }
}

extern "C" void kernel_launch(void* const* d_in, const int* in_sizes, int n_in,
                              void* d_out, int out_size, void* d_ws, size_t ws_size,
                              hipStream_t stream) {
    (void)d_ws; (void)ws_size; (void)n_in; (void)out_size;
    const float* inp = (const float*)d_in[0];
    float* out = (float*)d_out;
    const int B = in_sizes[0] / 12;
    rir_fused<<<dim3(B * 2), dim3(NT), 0, stream>>>(inp, out, B);
}

// Round 13
// 103.085 us; speedup vs baseline: 1.6890x; 1.0208x over previous
//
#include <hip/hip_runtime.h>

#define NIMG    4991
#define RIRLEN  3968
#define NT      512          // 8 waves per block
#define NGRP    4            // blocks per batch; grid = B*4 = 512 = 2 blocks/CU
#define KPT     10           // images per thread (10*512 = 5120 >= 4991)
#define INV_PI  0.31830988618379067f
#define SR_OVER_C 46.647230320699704f   // 16000 / 343

// ---- compile-time compact image-source table: all (x,y,z), |x|+|y|+|z| <= 15 ----
struct Tab { int v[NIMG]; };
static constexpr Tab make_tab() {
    Tab t{};
    int k = 0;
    for (int x = -15; x <= 15; ++x)
        for (int y = -15; y <= 15; ++y)
            for (int z = -15; z <= 15; ++z) {
                int ax = x < 0 ? -x : x;
                int ay = y < 0 ? -y : y;
                int az = z < 0 ? -z : z;
                if (ax + ay + az <= 15)
                    t.v[k++] = (x + 15) | ((y + 15) << 8) | ((z + 15) << 16);
            }
    return t;
}
__constant__ Tab c_tab = make_tab();

static __device__ __forceinline__ int iabs(int v) { return v < 0 ? -v : v; }

// __builtin_amdgcn_cvt_pkrtz returns __fp16-based ext vector (R10 lesson).
typedef __fp16 f16x2 __attribute__((ext_vector_type(2)));

// ============================================================================
// Fused kernel v15. Block = (batch b, group g in 0..3); grid B*4 = 512 =
// 2 blocks/CU (R12 lesson: 1 block/CU = 2 waves/SIMD cannot hide latency;
// occupancy fell to 12.3% and stalls dominated).
// Block g owns windows wi ≡ g (mod 4): g<2 -> 16 windows, g>=2 -> 15.
// OWNERSHIP FILTER: window wi needs buckets [4wi+1, 4wi+9]; for wi ≡ g (16
// buckets repeat) that is bk mod 16 in [4g+1, 4g+9] -> only 9/16 = 56% of
// images are histogrammed/sorted per block (kills the sort-duplication cost
// of 2 blocks/CU). Single geometry pass -> register arrays; single-wave
// shuffle scan (replaces 16-barrier Hillis-Steele; 5 barriers total);
// scatter from registers; per-window EVAL ranges known exactly from s_off;
// waves take windows by prefix-midpoint share (exact balance).
// EVAL: pre = Hp + cth0*(f16)Hcd + sth0*(f16)Hsd; v = mask(pre)*rcp(t-delay).
// xw==0 impossible: natural frac -> Sterbenz (dstore==delay<di exactly);
// frac==0 -> relative nudge di*2^-16 (R9-proven).
// Windows partition the output -> plain coalesced stores, no atomics on out.
// ============================================================================
__global__ __launch_bounds__(NT, 4)
void rir_fused(const float* __restrict__ inp, float* __restrict__ out, int B) {
    const int bx   = blockIdx.x;
    const int b    = bx >> 2;
    const int g    = bx & 3;
    const int tid  = threadIdx.x;
    const int lane = tid & 63;
    const int wv   = tid >> 6;               // 0..7
    const int q    = lane & 3;               // sub-cursor id

    __shared__ float2   s_dh[NIMG];          // bucket-sorted {delay, Hp}   (40KB)
    __shared__ unsigned s_cs[NIMG];          // packed f16 {Hp*cd, Hp*sd}   (20KB)
    __shared__ float    s_par[12];
    __shared__ int      s_h4[256][4];        // sub-hists -> cursors        (4KB)
    __shared__ int      s_off[257];          // bucket offsets              (1KB)

    for (int k = tid; k < 1024; k += NT) ((int*)s_h4)[k] = 0;
    if (tid == 0) {
        const float* ip = inp + b * 12;
        float rx = ip[0], ry = ip[1], rz = ip[2];
        float mx = ip[3] * rx, my = ip[4] * ry, mz = ip[5] * rz;
        float sx = ip[6] * rx, sy = ip[7] * ry, sz = ip[8] * rz;
        float aw = __builtin_fmaf(ip[9],  0.84f, 0.01f);
        float a4 = __builtin_fmaf(ip[10], 0.84f, 0.01f);
        float a5 = __builtin_fmaf(ip[11], 0.84f, 0.01f);
        s_par[0] = rx; s_par[1] = ry; s_par[2] = rz;
        s_par[3] = mx; s_par[4] = my; s_par[5] = mz;
        s_par[6] = sx; s_par[7] = sy; s_par[8] = sz;
        s_par[9]  = 0.5f * __builtin_amdgcn_logf(1.0f - aw);   // log2(tr)
        s_par[10] = 0.5f * __builtin_amdgcn_logf(1.0f - a4);
        s_par[11] = 0.5f * __builtin_amdgcn_logf(1.0f - a5);
        if (g == 0) {   // toa output, once per batch
            float dx = mx - sx, dy = my - sy, dz = mz - sz;
            out[(size_t)B * RIRLEN + b] = __builtin_fmaf(
                __builtin_sqrtf(dx * dx + dy * dy + dz * dz), SR_OVER_C, 40.0f);
        }
    }
    __syncthreads();                                           // B1

    const float rx = s_par[0], ry = s_par[1], rz = s_par[2];
    const float mx = s_par[3], my = s_par[4], mz = s_par[5];
    const float sx = s_par[6], sy = s_par[7], sz = s_par[8];
    const float lw = s_par[9], l4 = s_par[10], l5 = s_par[11];
    const int   fb = 4 * g + 1;              // first owned bucket (mod 16)

    // ---- SINGLE geometry pass -> registers; ownership filter; histogram ----
    float2   edh[KPT];
    unsigned ecs[KPT];
    int      bkt[KPT];
    #pragma unroll
    for (int k = 0; k < KPT; ++k) {
        bkt[k] = -1;
        const int idx = tid + k * NT;
        if (idx < NIMG) {
            const int p = c_tab.v[idx];
            const int x = (p & 255) - 15;
            const int y = ((p >> 8) & 255) - 15;
            const int z = ((p >> 16) & 255) - 15;
            const float ix = (x & 1) ? __builtin_fmaf(rx, (float)(x + 1), -sx)
                                     : __builtin_fmaf(rx, (float)x, sx);
            const float iy = (y & 1) ? __builtin_fmaf(ry, (float)(y + 1), -sy)
                                     : __builtin_fmaf(ry, (float)y, sy);
            const float iz = (z & 1) ? __builtin_fmaf(rz, (float)(z + 1), -sz)
                                     : __builtin_fmaf(rz, (float)z, sz);
            const float dx = ix - mx, dy = iy - my, dz = iz - mz;
            const float dist  = __builtin_sqrtf(
                __builtin_fmaf(dx, dx, __builtin_fmaf(dy, dy, dz * dz)));
            const float delay = dist * SR_OVER_C;
            const float di    = __builtin_ceilf(delay);
            const int   ti0   = (int)di - 40;
            const int   bk    = (ti0 + 96) >> 4;               // in [3,253]
            // owned iff bk mod 16 in [4g+1, 4g+9] (wrapping)
            const bool owned  = ((unsigned)((bk - fb + 16) & 15) < 9u);
            if (ti0 < RIRLEN && owned) {
                const int ew = iabs(x >> 1) + iabs((x + 1) >> 1)
                             + iabs(y >> 1) + iabs((y + 1) >> 1);
                const float att = __builtin_amdgcn_exp2f(__builtin_fmaf((float)ew, lw,
                                      __builtin_fmaf((float)iabs(z >> 1), l4,
                                           (float)iabs((z + 1) >> 1) * l5)));
                const float amp = att * __builtin_amdgcn_rcpf(dist);
                float frac = di - delay;                       // exact (Sterbenz)
                if (frac == 0.0f) frac = di * 1.52587890625e-05f;  // rel nudge
                const int dii = (int)di;
                float c1p = amp * __builtin_amdgcn_sinf(0.5f * frac) * INV_PI;
                if (dii & 1) c1p = -c1p;
                const float Hp     = 0.5f * c1p;
                const float dstore = di - frac;
                const float rv = dstore * 0.0125f;             // delay/80
                const float fr = rv - __builtin_floorf(rv);
                const float Hcd = Hp * __builtin_amdgcn_cosf(fr);  // revolutions
                const float Hsd = Hp * __builtin_amdgcn_sinf(fr);
                const f16x2 pk2 = __builtin_amdgcn_cvt_pkrtz(Hcd, Hsd);

                bkt[k] = bk;
                edh[k] = make_float2(dstore, Hp);
                ecs[k] = __builtin_bit_cast(unsigned, pk2);
                atomicAdd(&s_h4[bk][q], 1);
            }
        }
    }
    __syncthreads();                                           // B2

    // ---- single-wave shuffle scan over 256 buckets (wave 0 only) ----
    if (wv == 0) {
        const int l = lane;
        const int4 a0 = *(const int4*)&s_h4[4 * l + 0][0];
        const int4 a1 = *(const int4*)&s_h4[4 * l + 1][0];
        const int4 a2 = *(const int4*)&s_h4[4 * l + 2][0];
        const int4 a3 = *(const int4*)&s_h4[4 * l + 3][0];
        const int c0 = a0.x + a0.y + a0.z + a0.w;
        const int c1 = a1.x + a1.y + a1.z + a1.w;
        const int c2 = a2.x + a2.y + a2.z + a2.w;
        const int c3 = a3.x + a3.y + a3.z + a3.w;
        const int ts = c0 + c1 + c2 + c3;
        int incl = ts;
        #pragma unroll
        for (int d = 1; d < 64; d <<= 1) {
            const int u = __shfl_up(incl, d, 64);
            if (l >= d) incl += u;
        }
        const int base = incl - ts;
        s_off[4 * l + 0] = base;
        s_off[4 * l + 1] = base + c0;
        s_off[4 * l + 2] = base + c0 + c1;
        s_off[4 * l + 3] = base + c0 + c1 + c2;
        if (l == 63) s_off[256] = incl;
    }
    __syncthreads();                                           // B3

    if (tid < 256) {        // sub-histograms -> sub-cursors in place
        int run = s_off[tid];
        #pragma unroll
        for (int p = 0; p < 4; ++p) {
            const int c = s_h4[tid][p];
            s_h4[tid][p] = run;
            run += c;
        }
    }
    __syncthreads();                                           // B4

    // ---- scatter from registers into bucket-sorted LDS ----
    #pragma unroll
    for (int k = 0; k < KPT; ++k) {
        if (bkt[k] >= 0) {
            const int slot = atomicAdd(&s_h4[bkt[k]][q], 1);
            s_dh[slot] = edh[k];
            s_cs[slot] = ecs[k];
        }
    }
    __syncthreads();                                           // B5 (last)

    // ---- exact balance over this block's owned windows (wi = g + 4k) ----
    int T = 0;
    #pragma unroll
    for (int kk = 0; kk < 16; ++kk) {
        const int wi = g + 4 * kk;
        if (wi < 62) T += s_off[4 * wi + 10] - s_off[4 * wi + 1];
    }

    int P = 0;
    #pragma unroll
    for (int kk = 0; kk < 16; ++kk) {
        const int wi = g + 4 * kk;
        if (wi >= 62) break;
        const int lo  = s_off[4 * wi + 1];
        const int hi  = s_off[4 * wi + 10];
        const int len = hi - lo;
        int owner = (T > 0)
            ? (int)((8u * (unsigned)(P + (len >> 1))) / (unsigned)T)
            : (kk >> 1);
        if (owner > 7) owner = 7;
        P += len;
        if (owner != wv) continue;

        const int   t    = (wi << 6) + lane;
        const float tf   = (float)t;
        const int   m    = t - (t / 80) * 80;           // t mod 80
        const float cth0 = __builtin_amdgcn_cosf((float)m * 0.0125f);
        const float sth0 = __builtin_amdgcn_sinf((float)m * 0.0125f);
        const float sl   = (lane & 1) ? -1.0f : 1.0f;   // (-1)^t, wi*64 even

        float acc = 0.0f;
        #pragma unroll 4
        for (int i = lo; i < hi; ++i) {
            const float2 e  = s_dh[i];                  // uniform b64 broadcast
            const f16x2  h  = __builtin_bit_cast(f16x2, s_cs[i]);  // b32
            const float xw  = tf - e.x;
            const float pre = __builtin_fmaf(cth0, (float)h.x,
                                  __builtin_fmaf(sth0, (float)h.y, e.y));
            const float hm  = (__builtin_fabsf(xw) <= 40.0f) ? pre : 0.0f;
            acc = __builtin_fmaf(hm, __builtin_amdgcn_rcpf(xw), acc);
        }
        out[(size_t)b * RIRLEN + t] = sl * acc;         // plain coalesced store
    }
}

extern "C" void kernel_launch(void* const* d_in, const int* in_sizes, int n_in,
                              void* d_out, int out_size, void* d_ws, size_t ws_size,
                              hipStream_t stream) {
    (void)d_ws; (void)ws_size; (void)n_in; (void)out_size;
    const float* inp = (const float*)d_in[0];
    float* out = (float*)d_out;
    const int B = in_sizes[0] / 12;
    rir_fused<<<dim3(B * NGRP), dim3(NT), 0, stream>>>(inp, out, B);
}

// Round 14
// 100.037 us; speedup vs baseline: 1.7405x; 1.0305x over previous
//
#include <hip/hip_runtime.h>

#define NIMG    4991
#define RIRLEN  3968
#define NT      512          // 8 waves per block
#define NGRP    8            // blocks per batch; grid = B*8 = 1024 (2 rounds/CU)
#define KPT     10           // images per thread (10*512 = 5120 >= 4991)
#define INV_PI  0.31830988618379067f
#define SR_OVER_C 46.647230320699704f   // 16000 / 343

// ---- compile-time compact image-source table: all (x,y,z), |x|+|y|+|z| <= 15 ----
struct Tab { int v[NIMG]; };
static constexpr Tab make_tab() {
    Tab t{};
    int k = 0;
    for (int x = -15; x <= 15; ++x)
        for (int y = -15; y <= 15; ++y)
            for (int z = -15; z <= 15; ++z) {
                int ax = x < 0 ? -x : x;
                int ay = y < 0 ? -y : y;
                int az = z < 0 ? -z : z;
                if (ax + ay + az <= 15)
                    t.v[k++] = (x + 15) | ((y + 15) << 8) | ((z + 15) << 16);
            }
    return t;
}
__constant__ Tab c_tab = make_tab();

static __device__ __forceinline__ int iabs(int v) { return v < 0 ? -v : v; }

// __builtin_amdgcn_cvt_pkrtz returns __fp16-based ext vector (R10 lesson).
typedef __fp16 f16x2 __attribute__((ext_vector_type(2)));

// ============================================================================
// Fused kernel v16. Block = (batch b, group g in 0..7); grid B*8 = 1024
// (2 resident/CU -> 2 rounds + backfill: cross-batch skew smoothing; R13's
// grid==resident left 57% drain). Block g owns windows wi ≡ g (mod 8); their
// bucket ranges [4wi+1, 4wi+10) are DISJOINT (stride 32 > width 9), and the
// ownership filter keeps only bk mod 32 in [4g+1, 4g+9] -> 28% of images
// sorted per block (8 x 28% = same total sort work as R13's 4 x 56%).
// Single geometry pass -> registers; histogram atomicAdd RETURNS each image's
// rank -> scatter is rank+base plain ds_write (no second atomic pass).
// Intra-block balance: wave w evals concatenated-range slice
// [T*w/8, T*(w+1)/8) across the block's <=8 windows (chunk granularity = 1
// image); partials merge via 8x64 LDS float accumulator (+1 barrier).
// EVAL reads 2 images/iter: ds_read_b128 {d,Hp}x2 + b64 {pk}x2 -> 1 DS
// op/image instead of 2. EVAL: pre = Hp + cth0*Hcd + sth0*Hsd;
// v = mask(pre)*rcp(t-delay). xw==0 impossible (Sterbenz / relative nudge
// di*2^-16, R9-proven). Windows partition the output -> plain stores.
// ============================================================================
__global__ __launch_bounds__(NT, 4)
void rir_fused(const float* __restrict__ inp, float* __restrict__ out, int B) {
    const int bx   = blockIdx.x;
    const int b    = bx >> 3;
    const int g    = bx & 7;
    const int tid  = threadIdx.x;
    const int lane = tid & 63;
    const int wv   = tid >> 6;               // 0..7
    const int q    = lane & 3;               // sub-cursor id

    __shared__ __align__(16) float2   s_dh[NIMG];   // sorted {delay, Hp}  (40KB)
    __shared__ __align__(8)  unsigned s_cs[NIMG];   // packed f16 {Hcd,Hsd}(20KB)
    __shared__ float    s_par[12];
    __shared__ int      s_h4[256][4];        // sub-hists -> base cursors  (4KB)
    __shared__ int      s_off[257];          // bucket offsets             (1KB)
    __shared__ float    s_acc[8][64];        // per-window accumulators    (2KB)

    for (int k = tid; k < 1024; k += NT) ((int*)s_h4)[k] = 0;
    if (tid < 512) ((float*)s_acc)[tid] = 0.0f;
    if (tid == 0) {
        const float* ip = inp + b * 12;
        float rx = ip[0], ry = ip[1], rz = ip[2];
        float mx = ip[3] * rx, my = ip[4] * ry, mz = ip[5] * rz;
        float sx = ip[6] * rx, sy = ip[7] * ry, sz = ip[8] * rz;
        float aw = __builtin_fmaf(ip[9],  0.84f, 0.01f);
        float a4 = __builtin_fmaf(ip[10], 0.84f, 0.01f);
        float a5 = __builtin_fmaf(ip[11], 0.84f, 0.01f);
        s_par[0] = rx; s_par[1] = ry; s_par[2] = rz;
        s_par[3] = mx; s_par[4] = my; s_par[5] = mz;
        s_par[6] = sx; s_par[7] = sy; s_par[8] = sz;
        s_par[9]  = 0.5f * __builtin_amdgcn_logf(1.0f - aw);   // log2(tr)
        s_par[10] = 0.5f * __builtin_amdgcn_logf(1.0f - a4);
        s_par[11] = 0.5f * __builtin_amdgcn_logf(1.0f - a5);
        if (g == 0) {   // toa output, once per batch
            float dx = mx - sx, dy = my - sy, dz = mz - sz;
            out[(size_t)B * RIRLEN + b] = __builtin_fmaf(
                __builtin_sqrtf(dx * dx + dy * dy + dz * dz), SR_OVER_C, 40.0f);
        }
    }
    __syncthreads();                                           // B1

    const float rx = s_par[0], ry = s_par[1], rz = s_par[2];
    const float mx = s_par[3], my = s_par[4], mz = s_par[5];
    const float sx = s_par[6], sy = s_par[7], sz = s_par[8];
    const float lw = s_par[9], l4 = s_par[10], l5 = s_par[11];
    const int   fb = (4 * g + 1) & 31;       // first owned bucket (mod 32)

    // ---- SINGLE geometry pass -> registers; filter; histogram (rank kept) ----
    float2   edh[KPT];
    unsigned ecs[KPT];
    int      enc[KPT];                       // (bk<<13)|rank, or -1
    #pragma unroll
    for (int k = 0; k < KPT; ++k) {
        enc[k] = -1;
        const int idx = tid + k * NT;
        if (idx < NIMG) {
            const int p = c_tab.v[idx];
            const int x = (p & 255) - 15;
            const int y = ((p >> 8) & 255) - 15;
            const int z = ((p >> 16) & 255) - 15;
            const float ix = (x & 1) ? __builtin_fmaf(rx, (float)(x + 1), -sx)
                                     : __builtin_fmaf(rx, (float)x, sx);
            const float iy = (y & 1) ? __builtin_fmaf(ry, (float)(y + 1), -sy)
                                     : __builtin_fmaf(ry, (float)y, sy);
            const float iz = (z & 1) ? __builtin_fmaf(rz, (float)(z + 1), -sz)
                                     : __builtin_fmaf(rz, (float)z, sz);
            const float dx = ix - mx, dy = iy - my, dz = iz - mz;
            const float dist  = __builtin_sqrtf(
                __builtin_fmaf(dx, dx, __builtin_fmaf(dy, dy, dz * dz)));
            const float delay = dist * SR_OVER_C;
            const float di    = __builtin_ceilf(delay);
            const int   ti0   = (int)di - 40;
            const int   bk    = (ti0 + 96) >> 4;               // in [3,253]
            const bool owned  = ((unsigned)((bk - fb + 32) & 31) < 9u);
            if (ti0 < RIRLEN && owned) {
                const int ew = iabs(x >> 1) + iabs((x + 1) >> 1)
                             + iabs(y >> 1) + iabs((y + 1) >> 1);
                const float att = __builtin_amdgcn_exp2f(__builtin_fmaf((float)ew, lw,
                                      __builtin_fmaf((float)iabs(z >> 1), l4,
                                           (float)iabs((z + 1) >> 1) * l5)));
                const float amp = att * __builtin_amdgcn_rcpf(dist);
                float frac = di - delay;                       // exact (Sterbenz)
                if (frac == 0.0f) frac = di * 1.52587890625e-05f;  // rel nudge
                const int dii = (int)di;
                float c1p = amp * __builtin_amdgcn_sinf(0.5f * frac) * INV_PI;
                if (dii & 1) c1p = -c1p;
                const float Hp     = 0.5f * c1p;
                const float dstore = di - frac;
                const float rv = dstore * 0.0125f;             // delay/80
                const float fr = rv - __builtin_floorf(rv);
                const float Hcd = Hp * __builtin_amdgcn_cosf(fr);
                const float Hsd = Hp * __builtin_amdgcn_sinf(fr);
                const f16x2 pk2 = __builtin_amdgcn_cvt_pkrtz(Hcd, Hsd);

                const int rnk = atomicAdd(&s_h4[bk][q], 1);    // rank kept!
                enc[k] = (bk << 13) | rnk;
                edh[k] = make_float2(dstore, Hp);
                ecs[k] = __builtin_bit_cast(unsigned, pk2);
            }
        }
    }
    __syncthreads();                                           // B2

    // ---- single-wave shuffle scan over 256 buckets (wave 0 only) ----
    if (wv == 0) {
        const int l = lane;
        const int4 a0 = *(const int4*)&s_h4[4 * l + 0][0];
        const int4 a1 = *(const int4*)&s_h4[4 * l + 1][0];
        const int4 a2 = *(const int4*)&s_h4[4 * l + 2][0];
        const int4 a3 = *(const int4*)&s_h4[4 * l + 3][0];
        const int c0 = a0.x + a0.y + a0.z + a0.w;
        const int c1 = a1.x + a1.y + a1.z + a1.w;
        const int c2 = a2.x + a2.y + a2.z + a2.w;
        const int c3 = a3.x + a3.y + a3.z + a3.w;
        const int ts = c0 + c1 + c2 + c3;
        int incl = ts;
        #pragma unroll
        for (int d = 1; d < 64; d <<= 1) {
            const int u = __shfl_up(incl, d, 64);
            if (l >= d) incl += u;
        }
        const int base = incl - ts;
        s_off[4 * l + 0] = base;
        s_off[4 * l + 1] = base + c0;
        s_off[4 * l + 2] = base + c0 + c1;
        s_off[4 * l + 3] = base + c0 + c1 + c2;
        if (l == 63) s_off[256] = incl;
    }
    __syncthreads();                                           // B3

    if (tid < 256) {        // sub-histogram counts -> per-(bk,q) BASE cursors
        int run = s_off[tid];
        #pragma unroll
        for (int p = 0; p < 4; ++p) {
            const int c = s_h4[tid][p];
            s_h4[tid][p] = run;
            run += c;
        }
    }
    __syncthreads();                                           // B4

    // ---- scatter: slot = base[bk][q] + rank (NO atomics, plain writes) ----
    #pragma unroll
    for (int k = 0; k < KPT; ++k) {
        if (enc[k] >= 0) {
            const int bk   = enc[k] >> 13;
            const int slot = s_h4[bk][q] + (enc[k] & 8191);
            s_dh[slot] = edh[k];
            s_cs[slot] = ecs[k];
        }
    }
    __syncthreads();                                           // B5

    // ---- window table (registers) + exact chunked wave assignment ----
    int wlo[8], wlen[8], wpre[8];
    int T = 0, nw = 0;
    #pragma unroll
    for (int kk = 0; kk < 8; ++kk) {
        const int wi = g + 8 * kk;
        wpre[kk] = T;
        if (wi < 62) {
            wlo[kk]  = s_off[4 * wi + 1];
            wlen[kk] = s_off[4 * wi + 10] - wlo[kk];
            T += wlen[kk];
            nw = kk + 1;
        } else { wlo[kk] = 0; wlen[kk] = 0; }
    }
    const int a0r = (T * wv) >> 3;           // this wave's slice [a0r, a1r)
    const int a1r = (T * (wv + 1)) >> 3;

#define EV1(DLY, HPV, PKU) do {                                              \
        const f16x2 hh = __builtin_bit_cast(f16x2, (PKU));                   \
        const float xw = tf - (DLY);                                         \
        const float pre = __builtin_fmaf(cth0, (float)hh.x,                  \
                              __builtin_fmaf(sth0, (float)hh.y, (HPV)));     \
        const float hm = (__builtin_fabsf(xw) <= 40.0f) ? pre : 0.0f;        \
        acc = __builtin_fmaf(hm, __builtin_amdgcn_rcpf(xw), acc);            \
    } while (0)

    #pragma unroll
    for (int kk = 0; kk < 8; ++kk) {
        if (wlen[kk] == 0) continue;
        const int o0 = (wpre[kk] > a0r) ? wpre[kk] : a0r;
        const int oe = ((wpre[kk] + wlen[kk]) < a1r) ? (wpre[kk] + wlen[kk]) : a1r;
        if (o0 >= oe) continue;
        int       i  = wlo[kk] + (o0 - wpre[kk]);
        const int ie = wlo[kk] + (oe - wpre[kk]);

        const int   wi   = g + 8 * kk;
        const int   t    = (wi << 6) + lane;
        const float tf   = (float)t;
        const int   m    = t - (t / 80) * 80;           // t mod 80
        const float cth0 = __builtin_amdgcn_cosf((float)m * 0.0125f);
        const float sth0 = __builtin_amdgcn_sinf((float)m * 0.0125f);

        float acc = 0.0f;
        if ((i < ie) && (i & 1)) {           // align to even for paired reads
            EV1(s_dh[i].x, s_dh[i].y, s_cs[i]); ++i;
        }
        for (; i + 2 <= ie; i += 2) {        // 2 images: 1 b128 + 1 b64
            const float4 dd = *(const float4*)&s_dh[i];
            const uint2  cc = *(const uint2*)&s_cs[i];
            EV1(dd.x, dd.y, cc.x);
            EV1(dd.z, dd.w, cc.y);
        }
        if (i < ie) EV1(s_dh[i].x, s_dh[i].y, s_cs[i]);

        atomicAdd(&s_acc[kk][lane], acc);    // merge partial (rarely shared)
    }
#undef EV1
    __syncthreads();                                           // B6 (last)

    // ---- store: windows partition the output; sign (-1)^t applied here ----
    if (tid < 64 * nw) {
        const int kk = tid >> 6;
        const int wi = g + 8 * kk;
        const int t  = (wi << 6) + lane;
        const float sl = (lane & 1) ? -1.0f : 1.0f;     // wi*64 even
        out[(size_t)b * RIRLEN + t] = sl * s_acc[kk][lane];
    }
}

extern "C" void kernel_launch(void* const* d_in, const int* in_sizes, int n_in,
                              void* d_out, int out_size, void* d_ws, size_t ws_size,
                              hipStream_t stream) {
    (void)d_ws; (void)ws_size; (void)n_in; (void)out_size;
    const float* inp = (const float*)d_in[0];
    float* out = (float*)d_out;
    const int B = in_sizes[0] / 12;
    rir_fused<<<dim3(B * NGRP), dim3(NT), 0, stream>>>(inp, out, B);
}

// Round 15
// 97.058 us; speedup vs baseline: 1.7939x; 1.0307x over previous
//
#include <hip/hip_runtime.h>

#define NIMG    4991
#define RIRLEN  3968
#define NT      512          // 8 waves per block
#define NGRP    8            // blocks per batch; grid = B*8 = 1024 (2 rounds/CU)
#define KPT     10           // images per thread (10*512 = 5120 >= 4991)
#define INV_PI  0.31830988618379067f
#define SR_OVER_C 46.647230320699704f   // 16000 / 343

// ---- compile-time compact image-source table: all (x,y,z), |x|+|y|+|z| <= 15 ----
struct Tab { int v[NIMG]; };
static constexpr Tab make_tab() {
    Tab t{};
    int k = 0;
    for (int x = -15; x <= 15; ++x)
        for (int y = -15; y <= 15; ++y)
            for (int z = -15; z <= 15; ++z) {
                int ax = x < 0 ? -x : x;
                int ay = y < 0 ? -y : y;
                int az = z < 0 ? -z : z;
                if (ax + ay + az <= 15)
                    t.v[k++] = (x + 15) | ((y + 15) << 8) | ((z + 15) << 16);
            }
    return t;
}
__constant__ Tab c_tab = make_tab();

static __device__ __forceinline__ int iabs(int v) { return v < 0 ? -v : v; }

// __builtin_amdgcn_cvt_pkrtz returns __fp16-based ext vector (R10 lesson).
typedef __fp16 f16x2 __attribute__((ext_vector_type(2)));

// ============================================================================
// Fused kernel v17 = R14 structure + PER-AXIS LDS TABLES (the geometry pass,
// duplicated NGRP x per batch, was the R13->R14 regression; make it cheap
// instead of rare). Tables, computed once per block from s_par:
//   p2[a][n]  = (image_coord_a(n) - mic_a)^2        (31 entries per axis)
//   at[a][n]  = per-axis attenuation: x,y: tr_w^(e(n)); z: tr4^|n>>1|*tr5^|..|
// Geometry per image: dist2 = p2x+p2y+p2z (2 adds, 3 LDS b32), dist = sqrt,
// att = atx*aty*atz (2 muls, no exp2 trans). Rest identical to R14:
// rank-from-histogram scatter (no 2nd atomic pass), single-wave shuffle scan,
// chunk-granular wave balance, paired ds_read_b128/b64 EVAL (1 DS op/image),
// 8x64 LDS accumulator merge, windows partition output -> plain stores.
// xw==0 impossible (Sterbenz exact / relative nudge di*2^-16, R9-proven).
// ============================================================================
__global__ __launch_bounds__(NT, 4)
void rir_fused(const float* __restrict__ inp, float* __restrict__ out, int B) {
    const int bx   = blockIdx.x;
    const int b    = bx >> 3;
    const int g    = bx & 7;
    const int tid  = threadIdx.x;
    const int lane = tid & 63;
    const int wv   = tid >> 6;               // 0..7
    const int q    = lane & 3;               // sub-cursor id

    __shared__ __align__(16) float2   s_dh[NIMG];   // sorted {delay, Hp}  (40KB)
    __shared__ __align__(8)  unsigned s_cs[NIMG];   // packed f16 {Hcd,Hsd}(20KB)
    __shared__ float    s_par[12];
    __shared__ float    s_p2[3][32];         // per-axis (coord-mic)^2
    __shared__ float    s_at[3][32];         // per-axis attenuation factor
    __shared__ int      s_h4[256][4];        // sub-hists -> base cursors  (4KB)
    __shared__ int      s_off[257];          // bucket offsets             (1KB)
    __shared__ float    s_acc[8][64];        // per-window accumulators    (2KB)

    for (int k = tid; k < 1024; k += NT) ((int*)s_h4)[k] = 0;
    if (tid < 512) ((float*)s_acc)[tid] = 0.0f;
    if (tid == 0) {
        const float* ip = inp + b * 12;
        float rx = ip[0], ry = ip[1], rz = ip[2];
        float mx = ip[3] * rx, my = ip[4] * ry, mz = ip[5] * rz;
        float sx = ip[6] * rx, sy = ip[7] * ry, sz = ip[8] * rz;
        float aw = __builtin_fmaf(ip[9],  0.84f, 0.01f);
        float a4 = __builtin_fmaf(ip[10], 0.84f, 0.01f);
        float a5 = __builtin_fmaf(ip[11], 0.84f, 0.01f);
        s_par[0] = rx; s_par[1] = ry; s_par[2] = rz;
        s_par[3] = mx; s_par[4] = my; s_par[5] = mz;
        s_par[6] = sx; s_par[7] = sy; s_par[8] = sz;
        s_par[9]  = 0.5f * __builtin_amdgcn_logf(1.0f - aw);   // log2(tr)
        s_par[10] = 0.5f * __builtin_amdgcn_logf(1.0f - a4);
        s_par[11] = 0.5f * __builtin_amdgcn_logf(1.0f - a5);
        if (g == 0) {   // toa output, once per batch
            float dx = mx - sx, dy = my - sy, dz = mz - sz;
            out[(size_t)B * RIRLEN + b] = __builtin_fmaf(
                __builtin_sqrtf(dx * dx + dy * dy + dz * dz), SR_OVER_C, 40.0f);
        }
    }
    __syncthreads();                                           // B1: s_par ready

    // ---- per-axis tables (96 threads; needs s_par) ----
    if (tid < 96) {
        const int axis = tid >> 5;           // 0,1,2
        const int j    = tid & 31;           // table index
        if (j < 31) {
            const int n = j - 15;
            const float rr = s_par[axis];
            const float mm = s_par[3 + axis];
            const float ss = s_par[6 + axis];
            const float iv = (n & 1) ? __builtin_fmaf(rr, (float)(n + 1), -ss)
                                     : __builtin_fmaf(rr, (float)n, ss);
            const float pv = iv - mm;
            s_p2[axis][j] = pv * pv;
            const float e4 = (float)iabs(n >> 1);
            const float e5 = (float)iabs((n + 1) >> 1);
            const float ex = (axis < 2)
                ? (e4 + e5) * s_par[9]
                : __builtin_fmaf(e4, s_par[10], e5 * s_par[11]);
            s_at[axis][j] = __builtin_amdgcn_exp2f(ex);
        }
    }
    __syncthreads();                                           // B1b: tables ready

    const int fb = (4 * g + 1) & 31;         // first owned bucket (mod 32)

    // ---- SINGLE cheap geometry pass -> registers; filter; histogram ----
    float2   edh[KPT];
    unsigned ecs[KPT];
    int      enc[KPT];                       // (bk<<13)|rank, or -1
    #pragma unroll
    for (int k = 0; k < KPT; ++k) {
        enc[k] = -1;
        const int idx = tid + k * NT;
        if (idx < NIMG) {
            const int p  = c_tab.v[idx];
            const int xi = p & 255;
            const int yi = (p >> 8) & 255;
            const int zi = (p >> 16) & 255;
            const float d2   = s_p2[0][xi] + s_p2[1][yi] + s_p2[2][zi];
            const float dist = __builtin_sqrtf(d2);
            const float delay = dist * SR_OVER_C;
            const float di    = __builtin_ceilf(delay);
            const int   ti0   = (int)di - 40;
            const int   bk    = (ti0 + 96) >> 4;               // in [3,253]
            const bool owned  = ((unsigned)((bk - fb + 32) & 31) < 9u);
            if (ti0 < RIRLEN && owned) {
                const float att = s_at[0][xi] * s_at[1][yi] * s_at[2][zi];
                const float amp = att * __builtin_amdgcn_rcpf(dist);
                float frac = di - delay;                       // exact (Sterbenz)
                if (frac == 0.0f) frac = di * 1.52587890625e-05f;  // rel nudge
                const int dii = (int)di;
                float c1p = amp * __builtin_amdgcn_sinf(0.5f * frac) * INV_PI;
                if (dii & 1) c1p = -c1p;
                const float Hp     = 0.5f * c1p;
                const float dstore = di - frac;
                const float rv = dstore * 0.0125f;             // delay/80
                const float fr = rv - __builtin_floorf(rv);
                const float Hcd = Hp * __builtin_amdgcn_cosf(fr);
                const float Hsd = Hp * __builtin_amdgcn_sinf(fr);
                const f16x2 pk2 = __builtin_amdgcn_cvt_pkrtz(Hcd, Hsd);

                const int rnk = atomicAdd(&s_h4[bk][q], 1);    // rank kept
                enc[k] = (bk << 13) | rnk;
                edh[k] = make_float2(dstore, Hp);
                ecs[k] = __builtin_bit_cast(unsigned, pk2);
            }
        }
    }
    __syncthreads();                                           // B2

    // ---- single-wave shuffle scan over 256 buckets (wave 0 only) ----
    if (wv == 0) {
        const int l = lane;
        const int4 a0 = *(const int4*)&s_h4[4 * l + 0][0];
        const int4 a1 = *(const int4*)&s_h4[4 * l + 1][0];
        const int4 a2 = *(const int4*)&s_h4[4 * l + 2][0];
        const int4 a3 = *(const int4*)&s_h4[4 * l + 3][0];
        const int c0 = a0.x + a0.y + a0.z + a0.w;
        const int c1 = a1.x + a1.y + a1.z + a1.w;
        const int c2 = a2.x + a2.y + a2.z + a2.w;
        const int c3 = a3.x + a3.y + a3.z + a3.w;
        const int ts = c0 + c1 + c2 + c3;
        int incl = ts;
        #pragma unroll
        for (int d = 1; d < 64; d <<= 1) {
            const int u = __shfl_up(incl, d, 64);
            if (l >= d) incl += u;
        }
        const int base = incl - ts;
        s_off[4 * l + 0] = base;
        s_off[4 * l + 1] = base + c0;
        s_off[4 * l + 2] = base + c0 + c1;
        s_off[4 * l + 3] = base + c0 + c1 + c2;
        if (l == 63) s_off[256] = incl;
    }
    __syncthreads();                                           // B3

    if (tid < 256) {        // sub-histogram counts -> per-(bk,q) BASE cursors
        int run = s_off[tid];
        #pragma unroll
        for (int p = 0; p < 4; ++p) {
            const int c = s_h4[tid][p];
            s_h4[tid][p] = run;
            run += c;
        }
    }
    __syncthreads();                                           // B4

    // ---- scatter: slot = base[bk][q] + rank (plain writes, no atomics) ----
    #pragma unroll
    for (int k = 0; k < KPT; ++k) {
        if (enc[k] >= 0) {
            const int bk   = enc[k] >> 13;
            const int slot = s_h4[bk][q] + (enc[k] & 8191);
            s_dh[slot] = edh[k];
            s_cs[slot] = ecs[k];
        }
    }
    __syncthreads();                                           // B5

    // ---- window table (registers) + exact chunked wave assignment ----
    int wlo[8], wlen[8], wpre[8];
    int T = 0, nw = 0;
    #pragma unroll
    for (int kk = 0; kk < 8; ++kk) {
        const int wi = g + 8 * kk;
        wpre[kk] = T;
        if (wi < 62) {
            wlo[kk]  = s_off[4 * wi + 1];
            wlen[kk] = s_off[4 * wi + 10] - wlo[kk];
            T += wlen[kk];
            nw = kk + 1;
        } else { wlo[kk] = 0; wlen[kk] = 0; }
    }
    const int a0r = (T * wv) >> 3;           // this wave's slice [a0r, a1r)
    const int a1r = (T * (wv + 1)) >> 3;

#define EV1(DLY, HPV, PKU) do {                                              \
        const f16x2 hh = __builtin_bit_cast(f16x2, (PKU));                   \
        const float xw = tf - (DLY);                                         \
        const float pre = __builtin_fmaf(cth0, (float)hh.x,                  \
                              __builtin_fmaf(sth0, (float)hh.y, (HPV)));     \
        const float hm = (__builtin_fabsf(xw) <= 40.0f) ? pre : 0.0f;        \
        acc = __builtin_fmaf(hm, __builtin_amdgcn_rcpf(xw), acc);            \
    } while (0)

    #pragma unroll
    for (int kk = 0; kk < 8; ++kk) {
        if (wlen[kk] == 0) continue;
        const int o0 = (wpre[kk] > a0r) ? wpre[kk] : a0r;
        const int oe = ((wpre[kk] + wlen[kk]) < a1r) ? (wpre[kk] + wlen[kk]) : a1r;
        if (o0 >= oe) continue;
        int       i  = wlo[kk] + (o0 - wpre[kk]);
        const int ie = wlo[kk] + (oe - wpre[kk]);

        const int   wi   = g + 8 * kk;
        const int   t    = (wi << 6) + lane;
        const float tf   = (float)t;
        const int   m    = t - (t / 80) * 80;           // t mod 80
        const float cth0 = __builtin_amdgcn_cosf((float)m * 0.0125f);
        const float sth0 = __builtin_amdgcn_sinf((float)m * 0.0125f);

        float acc = 0.0f;
        if ((i < ie) && (i & 1)) {           // align to even for paired reads
            EV1(s_dh[i].x, s_dh[i].y, s_cs[i]); ++i;
        }
        for (; i + 2 <= ie; i += 2) {        // 2 images: 1 b128 + 1 b64
            const float4 dd = *(const float4*)&s_dh[i];
            const uint2  cc = *(const uint2*)&s_cs[i];
            EV1(dd.x, dd.y, cc.x);
            EV1(dd.z, dd.w, cc.y);
        }
        if (i < ie) EV1(s_dh[i].x, s_dh[i].y, s_cs[i]);

        atomicAdd(&s_acc[kk][lane], acc);    // merge partial (rarely shared)
    }
#undef EV1
    __syncthreads();                                           // B6 (last)

    // ---- store: windows partition the output; sign (-1)^t applied here ----
    if (tid < 64 * nw) {
        const int kk = tid >> 6;
        const int wi = g + 8 * kk;
        const int t  = (wi << 6) + lane;
        const float sl = (lane & 1) ? -1.0f : 1.0f;     // wi*64 even
        out[(size_t)b * RIRLEN + t] = sl * s_acc[kk][lane];
    }
}

extern "C" void kernel_launch(void* const* d_in, const int* in_sizes, int n_in,
                              void* d_out, int out_size, void* d_ws, size_t ws_size,
                              hipStream_t stream) {
    (void)d_ws; (void)ws_size; (void)n_in; (void)out_size;
    const float* inp = (const float*)d_in[0];
    float* out = (float*)d_out;
    const int B = in_sizes[0] / 12;
    rir_fused<<<dim3(B * NGRP), dim3(NT), 0, stream>>>(inp, out, B);
}

// Round 16
// 96.605 us; speedup vs baseline: 1.8023x; 1.0047x over previous
//
#include <hip/hip_runtime.h>

#define NIMG    4991
#define RIRLEN  3968
#define NT      512          // 8 waves per block
#define NGRP    8            // blocks per batch; grid = B*8 = 1024 (2 rounds/CU)
#define KPT     10           // images per thread (10*512 = 5120 >= 4991)
#define INV_PI  0.31830988618379067f
#define SR_OVER_C 46.647230320699704f   // 16000 / 343

// ---- compile-time compact image-source table: all (x,y,z), |x|+|y|+|z| <= 15 ----
struct Tab { int v[NIMG]; };
static constexpr Tab make_tab() {
    Tab t{};
    int k = 0;
    for (int x = -15; x <= 15; ++x)
        for (int y = -15; y <= 15; ++y)
            for (int z = -15; z <= 15; ++z) {
                int ax = x < 0 ? -x : x;
                int ay = y < 0 ? -y : y;
                int az = z < 0 ? -z : z;
                if (ax + ay + az <= 15)
                    t.v[k++] = (x + 15) | ((y + 15) << 8) | ((z + 15) << 16);
            }
    return t;
}
__constant__ Tab c_tab = make_tab();

static __device__ __forceinline__ int iabs(int v) { return v < 0 ? -v : v; }

// __builtin_amdgcn_cvt_pkrtz returns __fp16-based ext vector (R10 lesson).
typedef __fp16 f16x2 __attribute__((ext_vector_type(2)));

// ============================================================================
// Fused kernel v19 = R15 + 8-WIDE EVAL BATCHES. R15 counter audit: per-SIMD
// issue ~10us but dispatch 51us -> EVAL loop is LDS-LATENCY-bound (2 images
// in flight, ~120cy ds_read latency vs ~30cy compute per iter). Fix: batch
// 8 images per iteration = 6 DS ops (4x b128 {delay,Hp} + 2x b128 = 8 packed
// f16 words), compiler stages lgkmcnt (m97-style), latency amortized 4x;
// two alternating accumulators break the acc-fma dependency chain.
// Remainder is 1-wide: slices may NOT over-read past ie (double-count).
// Rest identical to R15: per-axis LDS tables (cheap geometry), rank-from-
// histogram scatter (no 2nd atomic pass), single-wave shuffle scan, chunk-
// granular wave balance, 8x64 LDS accumulator merge, plain coalesced stores.
// xw==0 impossible (Sterbenz exact / relative nudge di*2^-16, R9-proven).
// ============================================================================
__global__ __launch_bounds__(NT, 4)
void rir_fused(const float* __restrict__ inp, float* __restrict__ out, int B) {
    const int bx   = blockIdx.x;
    const int b    = bx >> 3;
    const int g    = bx & 7;
    const int tid  = threadIdx.x;
    const int lane = tid & 63;
    const int wv   = tid >> 6;               // 0..7
    const int q    = lane & 3;               // sub-cursor id

    __shared__ __align__(16) float2   s_dh[NIMG];   // sorted {delay, Hp}  (40KB)
    __shared__ __align__(16) unsigned s_cs[NIMG];   // packed f16 {Hcd,Hsd}(20KB)
    __shared__ float    s_par[12];
    __shared__ float    s_p2[3][32];         // per-axis (coord-mic)^2
    __shared__ float    s_at[3][32];         // per-axis attenuation factor
    __shared__ int      s_h4[256][4];        // sub-hists -> base cursors  (4KB)
    __shared__ int      s_off[257];          // bucket offsets             (1KB)
    __shared__ float    s_acc[8][64];        // per-window accumulators    (2KB)

    for (int k = tid; k < 1024; k += NT) ((int*)s_h4)[k] = 0;
    if (tid < 512) ((float*)s_acc)[tid] = 0.0f;
    if (tid == 0) {
        const float* ip = inp + b * 12;
        float rx = ip[0], ry = ip[1], rz = ip[2];
        float mx = ip[3] * rx, my = ip[4] * ry, mz = ip[5] * rz;
        float sx = ip[6] * rx, sy = ip[7] * ry, sz = ip[8] * rz;
        float aw = __builtin_fmaf(ip[9],  0.84f, 0.01f);
        float a4 = __builtin_fmaf(ip[10], 0.84f, 0.01f);
        float a5 = __builtin_fmaf(ip[11], 0.84f, 0.01f);
        s_par[0] = rx; s_par[1] = ry; s_par[2] = rz;
        s_par[3] = mx; s_par[4] = my; s_par[5] = mz;
        s_par[6] = sx; s_par[7] = sy; s_par[8] = sz;
        s_par[9]  = 0.5f * __builtin_amdgcn_logf(1.0f - aw);   // log2(tr)
        s_par[10] = 0.5f * __builtin_amdgcn_logf(1.0f - a4);
        s_par[11] = 0.5f * __builtin_amdgcn_logf(1.0f - a5);
        if (g == 0) {   // toa output, once per batch
            float dx = mx - sx, dy = my - sy, dz = mz - sz;
            out[(size_t)B * RIRLEN + b] = __builtin_fmaf(
                __builtin_sqrtf(dx * dx + dy * dy + dz * dz), SR_OVER_C, 40.0f);
        }
    }
    __syncthreads();                                           // B1: s_par ready

    // ---- per-axis tables (96 threads; needs s_par) ----
    if (tid < 96) {
        const int axis = tid >> 5;           // 0,1,2
        const int j    = tid & 31;           // table index
        if (j < 31) {
            const int n = j - 15;
            const float rr = s_par[axis];
            const float mm = s_par[3 + axis];
            const float ss = s_par[6 + axis];
            const float iv = (n & 1) ? __builtin_fmaf(rr, (float)(n + 1), -ss)
                                     : __builtin_fmaf(rr, (float)n, ss);
            const float pv = iv - mm;
            s_p2[axis][j] = pv * pv;
            const float e4 = (float)iabs(n >> 1);
            const float e5 = (float)iabs((n + 1) >> 1);
            const float ex = (axis < 2)
                ? (e4 + e5) * s_par[9]
                : __builtin_fmaf(e4, s_par[10], e5 * s_par[11]);
            s_at[axis][j] = __builtin_amdgcn_exp2f(ex);
        }
    }
    __syncthreads();                                           // B1b: tables ready

    const int fb = (4 * g + 1) & 31;         // first owned bucket (mod 32)

    // ---- SINGLE cheap geometry pass -> registers; filter; histogram ----
    float2   edh[KPT];
    unsigned ecs[KPT];
    int      enc[KPT];                       // (bk<<13)|rank, or -1
    #pragma unroll
    for (int k = 0; k < KPT; ++k) {
        enc[k] = -1;
        const int idx = tid + k * NT;
        if (idx < NIMG) {
            const int p  = c_tab.v[idx];
            const int xi = p & 255;
            const int yi = (p >> 8) & 255;
            const int zi = (p >> 16) & 255;
            const float d2   = s_p2[0][xi] + s_p2[1][yi] + s_p2[2][zi];
            const float dist = __builtin_sqrtf(d2);
            const float delay = dist * SR_OVER_C;
            const float di    = __builtin_ceilf(delay);
            const int   ti0   = (int)di - 40;
            const int   bk    = (ti0 + 96) >> 4;               // in [3,253]
            const bool owned  = ((unsigned)((bk - fb + 32) & 31) < 9u);
            if (ti0 < RIRLEN && owned) {
                const float att = s_at[0][xi] * s_at[1][yi] * s_at[2][zi];
                const float amp = att * __builtin_amdgcn_rcpf(dist);
                float frac = di - delay;                       // exact (Sterbenz)
                if (frac == 0.0f) frac = di * 1.52587890625e-05f;  // rel nudge
                const int dii = (int)di;
                float c1p = amp * __builtin_amdgcn_sinf(0.5f * frac) * INV_PI;
                if (dii & 1) c1p = -c1p;
                const float Hp     = 0.5f * c1p;
                const float dstore = di - frac;
                const float rv = dstore * 0.0125f;             // delay/80
                const float fr = rv - __builtin_floorf(rv);
                const float Hcd = Hp * __builtin_amdgcn_cosf(fr);
                const float Hsd = Hp * __builtin_amdgcn_sinf(fr);
                const f16x2 pk2 = __builtin_amdgcn_cvt_pkrtz(Hcd, Hsd);

                const int rnk = atomicAdd(&s_h4[bk][q], 1);    // rank kept
                enc[k] = (bk << 13) | rnk;
                edh[k] = make_float2(dstore, Hp);
                ecs[k] = __builtin_bit_cast(unsigned, pk2);
            }
        }
    }
    __syncthreads();                                           // B2

    // ---- single-wave shuffle scan over 256 buckets (wave 0 only) ----
    if (wv == 0) {
        const int l = lane;
        const int4 a0 = *(const int4*)&s_h4[4 * l + 0][0];
        const int4 a1 = *(const int4*)&s_h4[4 * l + 1][0];
        const int4 a2 = *(const int4*)&s_h4[4 * l + 2][0];
        const int4 a3 = *(const int4*)&s_h4[4 * l + 3][0];
        const int c0 = a0.x + a0.y + a0.z + a0.w;
        const int c1 = a1.x + a1.y + a1.z + a1.w;
        const int c2 = a2.x + a2.y + a2.z + a2.w;
        const int c3 = a3.x + a3.y + a3.z + a3.w;
        const int ts = c0 + c1 + c2 + c3;
        int incl = ts;
        #pragma unroll
        for (int d = 1; d < 64; d <<= 1) {
            const int u = __shfl_up(incl, d, 64);
            if (l >= d) incl += u;
        }
        const int base = incl - ts;
        s_off[4 * l + 0] = base;
        s_off[4 * l + 1] = base + c0;
        s_off[4 * l + 2] = base + c0 + c1;
        s_off[4 * l + 3] = base + c0 + c1 + c2;
        if (l == 63) s_off[256] = incl;
    }
    __syncthreads();                                           // B3

    if (tid < 256) {        // sub-histogram counts -> per-(bk,q) BASE cursors
        int run = s_off[tid];
        #pragma unroll
        for (int p = 0; p < 4; ++p) {
            const int c = s_h4[tid][p];
            s_h4[tid][p] = run;
            run += c;
        }
    }
    __syncthreads();                                           // B4

    // ---- scatter: slot = base[bk][q] + rank (plain writes, no atomics) ----
    #pragma unroll
    for (int k = 0; k < KPT; ++k) {
        if (enc[k] >= 0) {
            const int bk   = enc[k] >> 13;
            const int slot = s_h4[bk][q] + (enc[k] & 8191);
            s_dh[slot] = edh[k];
            s_cs[slot] = ecs[k];
        }
    }
    __syncthreads();                                           // B5

    // ---- window table (registers) + exact chunked wave assignment ----
    int wlo[8], wlen[8], wpre[8];
    int T = 0, nw = 0;
    #pragma unroll
    for (int kk = 0; kk < 8; ++kk) {
        const int wi = g + 8 * kk;
        wpre[kk] = T;
        if (wi < 62) {
            wlo[kk]  = s_off[4 * wi + 1];
            wlen[kk] = s_off[4 * wi + 10] - wlo[kk];
            T += wlen[kk];
            nw = kk + 1;
        } else { wlo[kk] = 0; wlen[kk] = 0; }
    }
    const int a0r = (T * wv) >> 3;           // this wave's slice [a0r, a1r)
    const int a1r = (T * (wv + 1)) >> 3;

#define EV1(ACC, DLY, HPV, PKU) do {                                         \
        const f16x2 hh = __builtin_bit_cast(f16x2, (PKU));                   \
        const float xw = tf - (DLY);                                         \
        const float pre = __builtin_fmaf(cth0, (float)hh.x,                  \
                              __builtin_fmaf(sth0, (float)hh.y, (HPV)));     \
        const float hm = (__builtin_fabsf(xw) <= 40.0f) ? pre : 0.0f;        \
        ACC = __builtin_fmaf(hm, __builtin_amdgcn_rcpf(xw), ACC);            \
    } while (0)

    #pragma unroll
    for (int kk = 0; kk < 8; ++kk) {
        if (wlen[kk] == 0) continue;
        const int o0 = (wpre[kk] > a0r) ? wpre[kk] : a0r;
        const int oe = ((wpre[kk] + wlen[kk]) < a1r) ? (wpre[kk] + wlen[kk]) : a1r;
        if (o0 >= oe) continue;
        int       i  = wlo[kk] + (o0 - wpre[kk]);
        const int ie = wlo[kk] + (oe - wpre[kk]);

        const int   wi   = g + 8 * kk;
        const int   t    = (wi << 6) + lane;
        const float tf   = (float)t;
        const int   m    = t - (t / 80) * 80;           // t mod 80
        const float cth0 = __builtin_amdgcn_cosf((float)m * 0.0125f);
        const float sth0 = __builtin_amdgcn_sinf((float)m * 0.0125f);

        float acc0 = 0.0f, acc1 = 0.0f;
        // prologue: align i to 4 (b128 on s_cs needs 16B alignment)
        while (i < ie && (i & 3)) { EV1(acc0, s_dh[i].x, s_dh[i].y, s_cs[i]); ++i; }
        // main: 8 images / iter = 6 ds_read_b128 total, staged lgkmcnt
        for (; i + 8 <= ie; i += 8) {
            const float4 d0 = *(const float4*)&s_dh[i];
            const float4 d1 = *(const float4*)&s_dh[i + 2];
            const float4 d2 = *(const float4*)&s_dh[i + 4];
            const float4 d3 = *(const float4*)&s_dh[i + 6];
            const uint4  c0 = *(const uint4*)&s_cs[i];
            const uint4  c1 = *(const uint4*)&s_cs[i + 4];
            EV1(acc0, d0.x, d0.y, c0.x); EV1(acc1, d0.z, d0.w, c0.y);
            EV1(acc0, d1.x, d1.y, c0.z); EV1(acc1, d1.z, d1.w, c0.w);
            EV1(acc0, d2.x, d2.y, c1.x); EV1(acc1, d2.z, d2.w, c1.y);
            EV1(acc0, d3.x, d3.y, c1.z); EV1(acc1, d3.z, d3.w, c1.w);
        }
        // epilogue: strict bound (no over-read: slice sharing = double count)
        for (; i < ie; ++i) EV1(acc0, s_dh[i].x, s_dh[i].y, s_cs[i]);

        atomicAdd(&s_acc[kk][lane], acc0 + acc1);       // merge partial
    }
#undef EV1
    __syncthreads();                                           // B6 (last)

    // ---- store: windows partition the output; sign (-1)^t applied here ----
    if (tid < 64 * nw) {
        const int kk = tid >> 6;
        const int wi = g + 8 * kk;
        const int t  = (wi << 6) + lane;
        const float sl = (lane & 1) ? -1.0f : 1.0f;     // wi*64 even
        out[(size_t)b * RIRLEN + t] = sl * s_acc[kk][lane];
    }
}

extern "C" void kernel_launch(void* const* d_in, const int* in_sizes, int n_in,
                              void* d_out, int out_size, void* d_ws, size_t ws_size,
                              hipStream_t stream) {
    (void)d_ws; (void)ws_size; (void)n_in; (void)out_size;
    const float* inp = (const float*)d_in[0];
    float* out = (float*)d_out;
    const int B = in_sizes[0] / 12;
    rir_fused<<<dim3(B * NGRP), dim3(NT), 0, stream>>>(inp, out, B);
}